// Round 20
// baseline (138.446 us; speedup 1.0000x reference)
//
#include <hip/hip_runtime.h>
#include <hip/hip_bf16.h>

typedef short bf16x8 __attribute__((ext_vector_type(8)));
typedef float f32x4 __attribute__((ext_vector_type(4)));
#define MFMA16 __builtin_amdgcn_mfma_f32_16x16x32_bf16

// ---- split-bf16 helpers -----------------------------------------------------
// setup path (cold): bit-manip RNE
__device__ __forceinline__ unsigned short rne_bf16(float f) {
  unsigned u = __builtin_bit_cast(unsigned, f);
  return (unsigned short)((u + 0x7fffu + ((u >> 16) & 1u)) >> 16);
}
__device__ __forceinline__ float bf16f(unsigned short h) {
  unsigned u = ((unsigned)h) << 16;
  return __builtin_bit_cast(float, u);
}
__device__ __forceinline__ void split2_setup(float f, short& h, short& l) {
  unsigned short hh = rne_bf16(f);
  h = (short)hh;
  l = (short)rne_bf16(f - bf16f(hh));
}
// hot path: hardware v_cvt_bf16_f32 via compiler casts
__device__ __forceinline__ void split2(float f, short& h, short& l) {
  __hip_bfloat16 hb = __float2bfloat16(f);
  float hf = __bfloat162float(hb);
  __hip_bfloat16 lb = __float2bfloat16(f - hf);
  h = __builtin_bit_cast(short, hb);
  l = __builtin_bit_cast(short, lb);
}

// ---- ws layout (weights + bias only) ----------------------------------------
constexpr int NW_SH = 32768;   // node_W  256x128
constexpr int WC_SH = 16384;   // WcEt    128x128
constexpr int GF_SH = 65536;   // gfcn    128x512
constexpr int OFF_NWH = 0;
constexpr int OFF_NWL = NW_SH;
constexpr int OFF_WCH = 2 * NW_SH;
constexpr int OFF_WCL = 2 * NW_SH + WC_SH;
constexpr int OFF_GFH = 2 * NW_SH + 2 * WC_SH;
constexpr int OFF_GFL = 2 * NW_SH + 2 * WC_SH + GF_SH;
constexpr size_t OFF_BIAS_BYTES = (size_t)(2 * NW_SH + 2 * WC_SH + 2 * GF_SH) * 2; // 458752
constexpr size_t WS_NEED = OFF_BIAS_BYTES + 6 * 128 * 4;                            // ~462 KB

// ---- setup: pack weights into MFMA fragment layout (hi/lo bf16 planes) ------
__global__ __launch_bounds__(256) void setup_kernel(
    const float* __restrict__ node_W, const float* __restrict__ conv_W,
    const float* __restrict__ gfcn_W, const float* __restrict__ role_emb,
    const float* __restrict__ conv_b, const float* __restrict__ bn_gamma,
    const float* __restrict__ bn_beta, const float* __restrict__ bn_mean,
    const float* __restrict__ bn_var, short* __restrict__ wsS,
    float* __restrict__ bias_af) {
  int idx = blockIdx.x * 256 + threadIdx.x;
  int stride = gridDim.x * 256;
  for (int i = idx; i < 115456; i += stride) {
    if (i < 114688) {
      int j = i & 7, lane = (i >> 3) & 63;
      int kq = ((lane >> 4) & 3) * 8 + j, n16 = lane & 15;
      float val;
      short *ph, *pl;
      int loc;
      if (i < NW_SH) {
        loc = i;
        int f = i >> 9, kf = f & 7, nfr = f >> 3;
        int k = kf * 32 + kq, n = nfr * 16 + n16;
        val = node_W[k * 128 + n];
        ph = wsS + OFF_NWH; pl = wsS + OFF_NWL;
      } else if (i < NW_SH + WC_SH) {
        loc = i - NW_SH;
        int f = loc >> 9, kf = f & 3, nfr = f >> 2;
        int k = kf * 32 + kq, n = nfr * 16 + n16;
        float s = bn_gamma[n] * rsqrtf(bn_var[n] + 1e-5f);
        val = s * conv_W[n * 256 + 128 + k];     // WcEt[e=k][f=n]
        ph = wsS + OFF_WCH; pl = wsS + OFF_WCL;
      } else {
        loc = i - NW_SH - WC_SH;
        int f = loc >> 9, kf = f & 3, nfr = f >> 2;   // nfr 0..31
        int k = kf * 32 + kq, n = nfr * 16 + n16;     // n 0..511
        val = (n < 256) ? gfcn_W[k * 256 + n]
                        : gfcn_W[(128 + k) * 256 + (n - 256)];
        ph = wsS + OFF_GFH; pl = wsS + OFF_GFL;
      }
      short h, l;
      split2_setup(val, h, l);
      ph[loc] = h; pl[loc] = l;
    } else {
      int loc = i - 114688;
      int a = loc >> 7, fc = loc & 127;
      int role = (a == 5) ? 6 : a;   // ROLES = {0,1,2,3,4,6}
      float s = bn_gamma[fc] * rsqrtf(bn_var[fc] + 1e-5f);
      float dot = 0.f;
      for (int e = 0; e < 128; ++e)
        dot = fmaf(role_emb[role * 128 + e], conv_W[fc * 256 + e], dot);
      bias_af[loc] = s * (dot + conv_b[fc] - bn_mean[fc]) + bn_beta[fc];
    }
  }
}

// ---- fused2: R19 + merged A-frag batches in C/D (bigger MFMA clusters) ------
__global__ __launch_bounds__(512, 4) void fused2_kernel(
    const int* __restrict__ a_ids, const int* __restrict__ b_ids,
    const int* __restrict__ c_ids, const int* __restrict__ event_ids,
    const float* __restrict__ nf, const float* __restrict__ ent,
    const float* __restrict__ node_b, const float* __restrict__ cond,
    const float* __restrict__ text, const float* __restrict__ gfcn_b,
    const short* __restrict__ wsS, const float* __restrict__ bias_af,
    float* __restrict__ out) {
  __shared__ __align__(16) unsigned char smem[81920];
  short* lds_hi = (short*)smem;                 // 96x128 bf16 hi plane
  short* lds_lo = (short*)(smem + 24576);       // lo plane
  unsigned char* stage = smem + 49152;          // 32KB: B stage; D u/v mins
  float* umin_s = (float*)(smem + 49152);       // 16 x 256 f32 (after B)
  float* vmin_s = (float*)(smem + 49152 + 16384);

  const int t = threadIdx.x;
  const int wv = t >> 6, lane = t & 63;
  const int r15 = lane & 15, q = lane >> 4;
  const int tile = blockIdx.x;
  const int b0 = tile * 16;

  const bf16x8* nwh = (const bf16x8*)(wsS + OFF_NWH);
  const bf16x8* nwl = (const bf16x8*)(wsS + OFF_NWL);
  const bf16x8* wch = (const bf16x8*)(wsS + OFF_WCH);
  const bf16x8* wcl = (const bf16x8*)(wsS + OFF_WCL);
  const bf16x8* gfh = (const bf16x8*)(wsS + OFF_GFH);
  const bf16x8* gfl = (const bf16x8*)(wsS + OFF_GFL);

  // ids for all 4 columns at lane r15 (stack order a,event,b,c)
  int id0 = a_ids[b0 + r15], id1 = event_ids[b0 + r15];
  int id2 = b_ids[b0 + r15], id3 = c_ids[b0 + r15];

  // ---- STAGE(bb): wave wv stages rows {2wv, 2wv+1} of both a's in batch -----
  auto STAGE = [&](int bb) {
    #pragma unroll
    for (int i = 0; i < 4; ++i) {
      int aL = i >> 1;
      int rr = wv * 2 + (i & 1);
      int a = bb * 2 + aL;
      int ida = (a == 0) ? __shfl(id0, rr) : (a == 1) ? __shfl(id1, rr)
              : (a == 2) ? __shfl(id2, rr) : __shfl(id3, rr);
      int c16 = lane ^ (rr & 7);              // inverse-swizzled source slot
      const float* gp = nf + (size_t)ida * 256 + c16 * 4;
      __builtin_amdgcn_global_load_lds(
          (const __attribute__((address_space(1))) unsigned int*)(const void*)gp,
          (__attribute__((address_space(3))) unsigned int*)(void*)
              (stage + (aL * 16 + rr) * 1024),
          16, 0, 0);
    }
  };

  // ---- hoisted ev gathers for BOTH batches (latency hides under staging) ----
  const int aB0 = wv >> 2, nq = wv & 3;        // BCOMP wave role
  float ev0[8], ev1[8];
  {
    int a0 = 0 * 2 + aB0, a1 = 1 * 2 + aB0;
    int idm0 = (a0 == 0) ? id0 : (a0 == 1) ? id1 : (a0 == 2) ? id2 : id3;
    int idm1 = (a1 == 0) ? id0 : (a1 == 1) ? id1 : (a1 == 2) ? id2 : id3;
    #pragma unroll
    for (int j2 = 0; j2 < 2; ++j2) {
      int n8 = nq * 2 + j2;
      #pragma unroll
      for (int rg = 0; rg < 4; ++rg) {
        ev0[j2 * 4 + rg] =
            ent[(size_t)__shfl(idm0, q * 4 + rg) * 128 + n8 * 16 + r15];
        ev1[j2 * 4 + rg] =
            ent[(size_t)__shfl(idm1, q * 4 + rg) * 128 + n8 * 16 + r15];
      }
    }
  }

  // ---- CONVERT: wave-private in-place f32 -> hi/lo bf16 ---------------------
  auto CONVERT = [&]() {
    int rsel = lane & 3;
    int rr = (rsel >> 1) * 16 + wv * 2 + (rsel & 1);
    int k = lane >> 2;               // 0..15
    unsigned char* rowp = stage + rr * 1024;
    int r7 = rr & 7;
    float4 f[4];
    // all reads first (in-place safety under wave lockstep)
    #pragma unroll
    for (int ss = 0; ss < 2; ++ss) {
      int s = k + 16 * ss;
      f[2 * ss]     = *(const float4*)(rowp + (((2 * s)     ^ r7) * 16));
      f[2 * ss + 1] = *(const float4*)(rowp + (((2 * s + 1) ^ r7) * 16));
    }
    #pragma unroll
    for (int ss = 0; ss < 2; ++ss) {
      int s = k + 16 * ss;
      bf16x8 hi8, lo8;
      #pragma unroll
      for (int j = 0; j < 4; ++j) {
        short h, l;
        split2(f[2 * ss][j], h, l);     hi8[j] = h;     lo8[j] = l;
        split2(f[2 * ss + 1][j], h, l); hi8[4 + j] = h; lo8[4 + j] = l;
      }
      *(bf16x8*)(rowp + ((s ^ r7) * 16))       = hi8;
      *(bf16x8*)(rowp + 512 + ((s ^ r7) * 16)) = lo8;
    }
  };

  // ---- BCOMP(bb): wave (aL=wv>>2, nq=wv&3) computes n8 pair; no split2 ------
  auto BCOMP = [&](int bb, float (&ev)[8]) {
    int aL = aB0;
    int a = bb * 2 + aL;
    f32x4 acc[2];
    acc[0] = (f32x4){0.f, 0.f, 0.f, 0.f};
    acc[1] = (f32x4){0.f, 0.f, 0.f, 0.f};
    const unsigned char* base = stage + aL * 16384 + r15 * 1024;
    const int r7 = r15 & 7;
    #pragma unroll
    for (int ks = 0; ks < 8; ++ks) {
      int u = ks * 4 + q;                  // hi/lo slot index
      bf16x8 Fh = *(const bf16x8*)(base + ((u ^ r7) * 16));
      bf16x8 Fl = *(const bf16x8*)(base + 512 + ((u ^ r7) * 16));
      #pragma unroll
      for (int j2 = 0; j2 < 2; ++j2) {
        int n8 = nq * 2 + j2;
        bf16x8 bh = nwh[(n8 * 8 + ks) * 64 + lane];
        bf16x8 bl = nwl[(n8 * 8 + ks) * 64 + lane];
        acc[j2] = MFMA16(Fh, bh, acc[j2], 0, 0, 0);
        acc[j2] = MFMA16(Fl, bh, acc[j2], 0, 0, 0);
        acc[j2] = MFMA16(Fh, bl, acc[j2], 0, 0, 0);
      }
    }
    #pragma unroll
    for (int j2 = 0; j2 < 2; ++j2) {
      int n8 = nq * 2 + j2;
      int col = n8 * 16 + r15;
      float nb = node_b[col];
      #pragma unroll
      for (int rg = 0; rg < 4; ++rg) {
        float v = ev[j2 * 4 + rg] + fmaxf(acc[j2][rg] + nb, 0.f);
        short h, l; split2(v, h, l);
        int row = a * 16 + q * 4 + rg;
        int si = row * 128 + (col ^ ((row & 7) << 3));
        lds_hi[si] = h; lds_lo[si] = l;
      }
    }
  };

  // ---- Phase B ----
  STAGE(0);
  __builtin_amdgcn_sched_barrier(0);
  // cond/text rows (a=4,5) -> plane rows 64..95 (overlaps batch-0 stage)
  #pragma unroll
  for (int j = 0; j < 8; ++j) {
    int i = j * 512 + t;
    int arr = i >> 11, rem = i & 2047, r = rem >> 7, e = rem & 127;
    const float* src = arr ? text : cond;
    float v = src[(size_t)(b0 + r) * 128 + e];
    short h, l;
    split2(v, h, l);
    int row = (4 + arr) * 16 + r;
    int si = row * 128 + (e ^ ((row & 7) << 3));
    lds_hi[si] = h; lds_lo[si] = l;
  }
  asm volatile("s_waitcnt vmcnt(0)" ::: "memory");   // own stage rows landed
  __builtin_amdgcn_sched_barrier(0);
  CONVERT();                    // wave-private rows: no barrier needed before
  __syncthreads();              // all rows converted
  BCOMP(0, ev0);
  __syncthreads();              // batch-0 stage reads done before overwrite
  STAGE(1);
  asm volatile("s_waitcnt vmcnt(0)" ::: "memory");
  __builtin_amdgcn_sched_barrier(0);
  CONVERT();
  __syncthreads();
  BCOMP(1, ev1);
  __syncthreads();              // vals rows 0..63 + cond/text 64..95 in planes

  // ---- Stage C: x = relu(vals @ WcEt + bias_af); merged 6-row A batch -------
  {
    f32x4 xacc[6];
    #pragma unroll
    for (int a = 0; a < 6; ++a) xacc[a] = (f32x4){0.f, 0.f, 0.f, 0.f};
    #pragma unroll
    for (int ks = 0; ks < 4; ++ks) {
      int k0 = ks * 32 + q * 8;
      bf16x8 bh = wch[(wv * 4 + ks) * 64 + lane];
      bf16x8 bl = wcl[(wv * 4 + ks) * 64 + lane];
      bf16x8 ah[6], al[6];
      #pragma unroll
      for (int j = 0; j < 6; ++j) {
        int row = j * 16 + r15;
        int si = row * 128 + (k0 ^ ((row & 7) << 3));
        ah[j] = *(const bf16x8*)&lds_hi[si];
        al[j] = *(const bf16x8*)&lds_lo[si];
      }
      __builtin_amdgcn_s_setprio(1);
      #pragma unroll
      for (int j = 0; j < 6; ++j) {
        xacc[j] = MFMA16(ah[j], bh, xacc[j], 0, 0, 0);
        xacc[j] = MFMA16(al[j], bh, xacc[j], 0, 0, 0);
        xacc[j] = MFMA16(ah[j], bl, xacc[j], 0, 0, 0);
      }
      __builtin_amdgcn_s_setprio(0);
    }
    __syncthreads();   // all plane reads done before x overwrites
    #pragma unroll
    for (int a = 0; a < 6; ++a) {
      int col = wv * 16 + r15;
      float bv = bias_af[a * 128 + col];
      #pragma unroll
      for (int rg = 0; rg < 4; ++rg) {
        float v = fmaxf(xacc[a][rg] + bv, 0.f);
        short h, l; split2(v, h, l);
        int row = a * 16 + q * 4 + rg;
        int si = row * 128 + (col ^ ((row & 7) << 3));
        lds_hi[si] = h; lds_lo[si] = l;
      }
    }
  }
  __syncthreads();

  // ---- Stage D: 2 passes of acc[6][2]; merged 6-row A batch; 36-MFMA cluster
  #pragma unroll
  for (int gp = 0; gp < 2; ++gp) {
    f32x4 acc[6][2];
    #pragma unroll
    for (int a = 0; a < 6; ++a) {
      acc[a][0] = (f32x4){0.f, 0.f, 0.f, 0.f};
      acc[a][1] = (f32x4){0.f, 0.f, 0.f, 0.f};
    }
    #pragma unroll
    for (int ks = 0; ks < 4; ++ks) {
      int k0 = ks * 32 + q * 8;
      bf16x8 bh[2], bl[2];
      #pragma unroll
      for (int jn = 0; jn < 2; ++jn) {
        int nfg = wv * 4 + gp * 2 + jn;
        bh[jn] = gfh[(nfg * 4 + ks) * 64 + lane];
        bl[jn] = gfl[(nfg * 4 + ks) * 64 + lane];
      }
      bf16x8 ah[6], al[6];
      #pragma unroll
      for (int j = 0; j < 6; ++j) {
        int row = j * 16 + r15;
        int si = row * 128 + (k0 ^ ((row & 7) << 3));
        ah[j] = *(const bf16x8*)&lds_hi[si];
        al[j] = *(const bf16x8*)&lds_lo[si];
      }
      __builtin_amdgcn_s_setprio(1);
      #pragma unroll
      for (int jn = 0; jn < 2; ++jn) {
        #pragma unroll
        for (int j = 0; j < 6; ++j) {
          acc[j][jn] = MFMA16(ah[j], bh[jn], acc[j][jn], 0, 0, 0);
          acc[j][jn] = MFMA16(al[j], bh[jn], acc[j][jn], 0, 0, 0);
          acc[j][jn] = MFMA16(ah[j], bl[jn], acc[j][jn], 0, 0, 0);
        }
      }
      __builtin_amdgcn_s_setprio(0);
    }
    // per-pass min over a -> staggered LDS write (rows spread by quad q)
    float* dst = (wv < 4) ? umin_s : vmin_s;
    int cbase = (wv & 3) * 64 + gp * 32;
    #pragma unroll
    for (int jn = 0; jn < 2; ++jn) {
      int colg = cbase + jn * 16 + r15;
      int colx = colg ^ (q << 4);              // quad-staggered bank group
      #pragma unroll
      for (int rg = 0; rg < 4; ++rg) {
        float mm = fminf(
            fminf(fminf(acc[0][jn][rg], acc[1][jn][rg]), acc[2][jn][rg]),
            fminf(fminf(acc[3][jn][rg], acc[4][jn][rg]), acc[5][jn][rg]));
        dst[(q * 4 + rg) * 256 + colx] = mm;
      }
    }
  }
  __syncthreads();   // all u/v mins in LDS

  // ---- combine: out = relu(umin + vmin + gfcn_b) (inverse stagger on read) --
  #pragma unroll
  for (int j = 0; j < 8; ++j) {
    int i = j * 512 + t;
    int r = i >> 8, g = i & 255;
    int gx = g ^ ((r >> 2) << 4);              // writer quad = r>>2
    out[(size_t)(b0 + r) * 256 + g] =
        fmaxf(umin_s[r * 256 + gx] + vmin_s[r * 256 + gx] + gfcn_b[g], 0.f);
  }
}

extern "C" void kernel_launch(void* const* d_in, const int* in_sizes, int n_in,
                              void* d_out, int out_size, void* d_ws, size_t ws_size,
                              hipStream_t stream) {
  const int* a_ids = (const int*)d_in[0];
  const int* b_ids = (const int*)d_in[1];
  const int* c_ids = (const int*)d_in[2];
  const int* event_ids = (const int*)d_in[3];
  const float* node_features = (const float*)d_in[4];
  const float* cond_rel = (const float*)d_in[5];
  const float* text = (const float*)d_in[6];
  const float* entity_emb = (const float*)d_in[7];
  const float* role_emb = (const float*)d_in[8];
  const float* node_W = (const float*)d_in[9];
  const float* node_b = (const float*)d_in[10];
  const float* conv_W = (const float*)d_in[11];
  const float* conv_b = (const float*)d_in[12];
  const float* bn_gamma = (const float*)d_in[13];
  const float* bn_beta = (const float*)d_in[14];
  const float* bn_mean = (const float*)d_in[15];
  const float* bn_var = (const float*)d_in[16];
  const float* gfcn_W = (const float*)d_in[17];
  const float* gfcn_b = (const float*)d_in[18];
  float* out = (float*)d_out;

  short* wsS = (short*)d_ws;
  float* bias_af = (float*)((char*)d_ws + OFF_BIAS_BYTES);
  const int B = in_sizes[0];   // 32768
  const int NT = B / 16;       // 2048

  setup_kernel<<<452, 256, 0, stream>>>(node_W, conv_W, gfcn_W, role_emb,
                                        conv_b, bn_gamma, bn_beta, bn_mean,
                                        bn_var, wsS, bias_af);
  fused2_kernel<<<NT, 512, 0, stream>>>(
      a_ids, b_ids, c_ids, event_ids, node_features, entity_emb, node_b,
      cond_rel, text, gfcn_b, wsS, bias_af, out);
}

// Round 21
// 134.099 us; speedup vs baseline: 1.0324x; 1.0324x over previous
//
#include <hip/hip_runtime.h>
#include <hip/hip_bf16.h>

typedef short bf16x8 __attribute__((ext_vector_type(8)));
typedef float f32x4 __attribute__((ext_vector_type(4)));
#define MFMA16 __builtin_amdgcn_mfma_f32_16x16x32_bf16

// ---- split-bf16 helpers -----------------------------------------------------
// setup path (cold): bit-manip RNE
__device__ __forceinline__ unsigned short rne_bf16(float f) {
  unsigned u = __builtin_bit_cast(unsigned, f);
  return (unsigned short)((u + 0x7fffu + ((u >> 16) & 1u)) >> 16);
}
__device__ __forceinline__ float bf16f(unsigned short h) {
  unsigned u = ((unsigned)h) << 16;
  return __builtin_bit_cast(float, u);
}
__device__ __forceinline__ void split2_setup(float f, short& h, short& l) {
  unsigned short hh = rne_bf16(f);
  h = (short)hh;
  l = (short)rne_bf16(f - bf16f(hh));
}
// hot path: hardware v_cvt_bf16_f32 via compiler casts
__device__ __forceinline__ void split2(float f, short& h, short& l) {
  __hip_bfloat16 hb = __float2bfloat16(f);
  float hf = __bfloat162float(hb);
  __hip_bfloat16 lb = __float2bfloat16(f - hf);
  h = __builtin_bit_cast(short, hb);
  l = __builtin_bit_cast(short, lb);
}

// ---- ws layout (weights + bias only) ----------------------------------------
constexpr int NW_SH = 32768;   // node_W  256x128
constexpr int WC_SH = 16384;   // WcEt    128x128
constexpr int GF_SH = 65536;   // gfcn    128x512
constexpr int OFF_NWH = 0;
constexpr int OFF_NWL = NW_SH;
constexpr int OFF_WCH = 2 * NW_SH;
constexpr int OFF_WCL = 2 * NW_SH + WC_SH;
constexpr int OFF_GFH = 2 * NW_SH + 2 * WC_SH;
constexpr int OFF_GFL = 2 * NW_SH + 2 * WC_SH + GF_SH;
constexpr size_t OFF_BIAS_BYTES = (size_t)(2 * NW_SH + 2 * WC_SH + 2 * GF_SH) * 2; // 458752
constexpr size_t WS_NEED = OFF_BIAS_BYTES + 6 * 128 * 4;                            // ~462 KB

// ---- setup: pack weights into MFMA fragment layout (hi/lo bf16 planes) ------
__global__ __launch_bounds__(256) void setup_kernel(
    const float* __restrict__ node_W, const float* __restrict__ conv_W,
    const float* __restrict__ gfcn_W, const float* __restrict__ role_emb,
    const float* __restrict__ conv_b, const float* __restrict__ bn_gamma,
    const float* __restrict__ bn_beta, const float* __restrict__ bn_mean,
    const float* __restrict__ bn_var, short* __restrict__ wsS,
    float* __restrict__ bias_af) {
  int idx = blockIdx.x * 256 + threadIdx.x;
  int stride = gridDim.x * 256;
  for (int i = idx; i < 115456; i += stride) {
    if (i < 114688) {
      int j = i & 7, lane = (i >> 3) & 63;
      int kq = ((lane >> 4) & 3) * 8 + j, n16 = lane & 15;
      float val;
      short *ph, *pl;
      int loc;
      if (i < NW_SH) {
        loc = i;
        int f = i >> 9, kf = f & 7, nfr = f >> 3;
        int k = kf * 32 + kq, n = nfr * 16 + n16;
        val = node_W[k * 128 + n];
        ph = wsS + OFF_NWH; pl = wsS + OFF_NWL;
      } else if (i < NW_SH + WC_SH) {
        loc = i - NW_SH;
        int f = loc >> 9, kf = f & 3, nfr = f >> 2;
        int k = kf * 32 + kq, n = nfr * 16 + n16;
        float s = bn_gamma[n] * rsqrtf(bn_var[n] + 1e-5f);
        val = s * conv_W[n * 256 + 128 + k];     // WcEt[e=k][f=n]
        ph = wsS + OFF_WCH; pl = wsS + OFF_WCL;
      } else {
        loc = i - NW_SH - WC_SH;
        int f = loc >> 9, kf = f & 3, nfr = f >> 2;   // nfr 0..31
        int k = kf * 32 + kq, n = nfr * 16 + n16;     // n 0..511
        val = (n < 256) ? gfcn_W[k * 256 + n]
                        : gfcn_W[(128 + k) * 256 + (n - 256)];
        ph = wsS + OFF_GFH; pl = wsS + OFF_GFL;
      }
      short h, l;
      split2_setup(val, h, l);
      ph[loc] = h; pl[loc] = l;
    } else {
      int loc = i - 114688;
      int a = loc >> 7, fc = loc & 127;
      int role = (a == 5) ? 6 : a;   // ROLES = {0,1,2,3,4,6}
      float s = bn_gamma[fc] * rsqrtf(bn_var[fc] + 1e-5f);
      float dot = 0.f;
      for (int e = 0; e < 128; ++e)
        dot = fmaf(role_emb[role * 128 + e], conv_W[fc * 256 + e], dot);
      bias_af[loc] = s * (dot + conv_b[fc] - bn_mean[fc]) + bn_beta[fc];
    }
  }
}

// ---- fused2: R19 configuration (best: 134.4 us) -----------------------------
__global__ __launch_bounds__(512, 4) void fused2_kernel(
    const int* __restrict__ a_ids, const int* __restrict__ b_ids,
    const int* __restrict__ c_ids, const int* __restrict__ event_ids,
    const float* __restrict__ nf, const float* __restrict__ ent,
    const float* __restrict__ node_b, const float* __restrict__ cond,
    const float* __restrict__ text, const float* __restrict__ gfcn_b,
    const short* __restrict__ wsS, const float* __restrict__ bias_af,
    float* __restrict__ out) {
  __shared__ __align__(16) unsigned char smem[81920];
  short* lds_hi = (short*)smem;                 // 96x128 bf16 hi plane
  short* lds_lo = (short*)(smem + 24576);       // lo plane
  unsigned char* stage = smem + 49152;          // 32KB: B stage; D u/v mins
  float* umin_s = (float*)(smem + 49152);       // 16 x 256 f32 (after B)
  float* vmin_s = (float*)(smem + 49152 + 16384);

  const int t = threadIdx.x;
  const int wv = t >> 6, lane = t & 63;
  const int r15 = lane & 15, q = lane >> 4;
  const int tile = blockIdx.x;
  const int b0 = tile * 16;

  const bf16x8* nwh = (const bf16x8*)(wsS + OFF_NWH);
  const bf16x8* nwl = (const bf16x8*)(wsS + OFF_NWL);
  const bf16x8* wch = (const bf16x8*)(wsS + OFF_WCH);
  const bf16x8* wcl = (const bf16x8*)(wsS + OFF_WCL);
  const bf16x8* gfh = (const bf16x8*)(wsS + OFF_GFH);
  const bf16x8* gfl = (const bf16x8*)(wsS + OFF_GFL);

  // ids for all 4 columns at lane r15 (stack order a,event,b,c)
  int id0 = a_ids[b0 + r15], id1 = event_ids[b0 + r15];
  int id2 = b_ids[b0 + r15], id3 = c_ids[b0 + r15];

  // ---- STAGE(bb): wave wv stages rows {2wv, 2wv+1} of both a's in batch -----
  auto STAGE = [&](int bb) {
    #pragma unroll
    for (int i = 0; i < 4; ++i) {
      int aL = i >> 1;
      int rr = wv * 2 + (i & 1);
      int a = bb * 2 + aL;
      int ida = (a == 0) ? __shfl(id0, rr) : (a == 1) ? __shfl(id1, rr)
              : (a == 2) ? __shfl(id2, rr) : __shfl(id3, rr);
      int c16 = lane ^ (rr & 7);              // inverse-swizzled source slot
      const float* gp = nf + (size_t)ida * 256 + c16 * 4;
      __builtin_amdgcn_global_load_lds(
          (const __attribute__((address_space(1))) unsigned int*)(const void*)gp,
          (__attribute__((address_space(3))) unsigned int*)(void*)
              (stage + (aL * 16 + rr) * 1024),
          16, 0, 0);
    }
  };

  // ---- hoisted ev gathers for BOTH batches (latency hides under staging) ----
  const int aB0 = wv >> 2, nq = wv & 3;        // BCOMP wave role
  float ev0[8], ev1[8];
  {
    int a0 = 0 * 2 + aB0, a1 = 1 * 2 + aB0;
    int idm0 = (a0 == 0) ? id0 : (a0 == 1) ? id1 : (a0 == 2) ? id2 : id3;
    int idm1 = (a1 == 0) ? id0 : (a1 == 1) ? id1 : (a1 == 2) ? id2 : id3;
    #pragma unroll
    for (int j2 = 0; j2 < 2; ++j2) {
      int n8 = nq * 2 + j2;
      #pragma unroll
      for (int rg = 0; rg < 4; ++rg) {
        ev0[j2 * 4 + rg] =
            ent[(size_t)__shfl(idm0, q * 4 + rg) * 128 + n8 * 16 + r15];
        ev1[j2 * 4 + rg] =
            ent[(size_t)__shfl(idm1, q * 4 + rg) * 128 + n8 * 16 + r15];
      }
    }
  }

  // ---- CONVERT: wave-private in-place f32 -> hi/lo bf16 (bank-optimal) ------
  auto CONVERT = [&]() {
    int rsel = lane & 3;
    int rr = (rsel >> 1) * 16 + wv * 2 + (rsel & 1);
    int k = lane >> 2;               // 0..15
    unsigned char* rowp = stage + rr * 1024;
    int r7 = rr & 7;
    float4 f[4];
    // all reads first (in-place safety under wave lockstep)
    #pragma unroll
    for (int ss = 0; ss < 2; ++ss) {
      int s = k + 16 * ss;
      f[2 * ss]     = *(const float4*)(rowp + (((2 * s)     ^ r7) * 16));
      f[2 * ss + 1] = *(const float4*)(rowp + (((2 * s + 1) ^ r7) * 16));
    }
    #pragma unroll
    for (int ss = 0; ss < 2; ++ss) {
      int s = k + 16 * ss;
      bf16x8 hi8, lo8;
      #pragma unroll
      for (int j = 0; j < 4; ++j) {
        short h, l;
        split2(f[2 * ss][j], h, l);     hi8[j] = h;     lo8[j] = l;
        split2(f[2 * ss + 1][j], h, l); hi8[4 + j] = h; lo8[4 + j] = l;
      }
      *(bf16x8*)(rowp + ((s ^ r7) * 16))       = hi8;
      *(bf16x8*)(rowp + 512 + ((s ^ r7) * 16)) = lo8;
    }
  };

  // ---- BCOMP(bb): wave (aL=wv>>2, nq=wv&3) computes n8 pair; no split2 ------
  auto BCOMP = [&](int bb, float (&ev)[8]) {
    int aL = aB0;
    int a = bb * 2 + aL;
    f32x4 acc[2];
    acc[0] = (f32x4){0.f, 0.f, 0.f, 0.f};
    acc[1] = (f32x4){0.f, 0.f, 0.f, 0.f};
    const unsigned char* base = stage + aL * 16384 + r15 * 1024;
    const int r7 = r15 & 7;
    #pragma unroll
    for (int ks = 0; ks < 8; ++ks) {
      int u = ks * 4 + q;                  // hi/lo slot index
      bf16x8 Fh = *(const bf16x8*)(base + ((u ^ r7) * 16));
      bf16x8 Fl = *(const bf16x8*)(base + 512 + ((u ^ r7) * 16));
      #pragma unroll
      for (int j2 = 0; j2 < 2; ++j2) {
        int n8 = nq * 2 + j2;
        bf16x8 bh = nwh[(n8 * 8 + ks) * 64 + lane];
        bf16x8 bl = nwl[(n8 * 8 + ks) * 64 + lane];
        acc[j2] = MFMA16(Fh, bh, acc[j2], 0, 0, 0);
        acc[j2] = MFMA16(Fl, bh, acc[j2], 0, 0, 0);
        acc[j2] = MFMA16(Fh, bl, acc[j2], 0, 0, 0);
      }
    }
    #pragma unroll
    for (int j2 = 0; j2 < 2; ++j2) {
      int n8 = nq * 2 + j2;
      int col = n8 * 16 + r15;
      float nb = node_b[col];
      #pragma unroll
      for (int rg = 0; rg < 4; ++rg) {
        float v = ev[j2 * 4 + rg] + fmaxf(acc[j2][rg] + nb, 0.f);
        short h, l; split2(v, h, l);
        int row = a * 16 + q * 4 + rg;
        int si = row * 128 + (col ^ ((row & 7) << 3));
        lds_hi[si] = h; lds_lo[si] = l;
      }
    }
  };

  // ---- Phase B ----
  STAGE(0);
  __builtin_amdgcn_sched_barrier(0);
  // cond/text rows (a=4,5) -> plane rows 64..95 (overlaps batch-0 stage)
  #pragma unroll
  for (int j = 0; j < 8; ++j) {
    int i = j * 512 + t;
    int arr = i >> 11, rem = i & 2047, r = rem >> 7, e = rem & 127;
    const float* src = arr ? text : cond;
    float v = src[(size_t)(b0 + r) * 128 + e];
    short h, l;
    split2(v, h, l);
    int row = (4 + arr) * 16 + r;
    int si = row * 128 + (e ^ ((row & 7) << 3));
    lds_hi[si] = h; lds_lo[si] = l;
  }
  asm volatile("s_waitcnt vmcnt(0)" ::: "memory");   // own stage rows landed
  __builtin_amdgcn_sched_barrier(0);
  CONVERT();                    // wave-private rows: no barrier needed before
  __syncthreads();              // all rows converted
  BCOMP(0, ev0);
  __syncthreads();              // batch-0 stage reads done before overwrite
  STAGE(1);
  asm volatile("s_waitcnt vmcnt(0)" ::: "memory");
  __builtin_amdgcn_sched_barrier(0);
  CONVERT();
  __syncthreads();
  BCOMP(1, ev1);
  __syncthreads();              // vals rows 0..63 + cond/text 64..95 in planes

  // ---- Stage C: x = relu(vals @ WcEt + bias_af); wave owns n-frag wv --------
  {
    f32x4 xacc[6];
    #pragma unroll
    for (int a = 0; a < 6; ++a) xacc[a] = (f32x4){0.f, 0.f, 0.f, 0.f};
    #pragma unroll
    for (int ks = 0; ks < 4; ++ks) {
      int k0 = ks * 32 + q * 8;
      bf16x8 bh = wch[(wv * 4 + ks) * 64 + lane];
      bf16x8 bl = wcl[(wv * 4 + ks) * 64 + lane];
      #pragma unroll
      for (int ha = 0; ha < 2; ++ha) {
        bf16x8 ah[3], al[3];
        #pragma unroll
        for (int j = 0; j < 3; ++j) {
          int a = ha * 3 + j;
          int row = a * 16 + r15;
          int si = row * 128 + (k0 ^ ((row & 7) << 3));
          ah[j] = *(const bf16x8*)&lds_hi[si];
          al[j] = *(const bf16x8*)&lds_lo[si];
        }
        __builtin_amdgcn_s_setprio(1);
        #pragma unroll
        for (int j = 0; j < 3; ++j) {
          int a = ha * 3 + j;
          xacc[a] = MFMA16(ah[j], bh, xacc[a], 0, 0, 0);
          xacc[a] = MFMA16(al[j], bh, xacc[a], 0, 0, 0);
          xacc[a] = MFMA16(ah[j], bl, xacc[a], 0, 0, 0);
        }
        __builtin_amdgcn_s_setprio(0);
      }
    }
    __syncthreads();   // all plane reads done before x overwrites
    #pragma unroll
    for (int a = 0; a < 6; ++a) {
      int col = wv * 16 + r15;
      float bv = bias_af[a * 128 + col];
      #pragma unroll
      for (int rg = 0; rg < 4; ++rg) {
        float v = fmaxf(xacc[a][rg] + bv, 0.f);
        short h, l; split2(v, h, l);
        int row = a * 16 + q * 4 + rg;
        int si = row * 128 + (col ^ ((row & 7) << 3));
        lds_hi[si] = h; lds_lo[si] = l;
      }
    }
  }
  __syncthreads();

  // ---- Stage D: 2 passes of acc[6][2]; staggered u/v min writes -------------
  #pragma unroll
  for (int gp = 0; gp < 2; ++gp) {
    f32x4 acc[6][2];
    #pragma unroll
    for (int a = 0; a < 6; ++a) {
      acc[a][0] = (f32x4){0.f, 0.f, 0.f, 0.f};
      acc[a][1] = (f32x4){0.f, 0.f, 0.f, 0.f};
    }
    #pragma unroll
    for (int ks = 0; ks < 4; ++ks) {
      int k0 = ks * 32 + q * 8;
      bf16x8 bh[2], bl[2];
      #pragma unroll
      for (int jn = 0; jn < 2; ++jn) {
        int nfg = wv * 4 + gp * 2 + jn;
        bh[jn] = gfh[(nfg * 4 + ks) * 64 + lane];
        bl[jn] = gfl[(nfg * 4 + ks) * 64 + lane];
      }
      #pragma unroll
      for (int ha = 0; ha < 2; ++ha) {
        bf16x8 ah[3], al[3];
        #pragma unroll
        for (int j = 0; j < 3; ++j) {
          int row = (ha * 3 + j) * 16 + r15;
          int si = row * 128 + (k0 ^ ((row & 7) << 3));
          ah[j] = *(const bf16x8*)&lds_hi[si];
          al[j] = *(const bf16x8*)&lds_lo[si];
        }
        __builtin_amdgcn_s_setprio(1);
        #pragma unroll
        for (int jn = 0; jn < 2; ++jn) {
          #pragma unroll
          for (int j = 0; j < 3; ++j) {
            int a = ha * 3 + j;
            acc[a][jn] = MFMA16(ah[j], bh[jn], acc[a][jn], 0, 0, 0);
            acc[a][jn] = MFMA16(al[j], bh[jn], acc[a][jn], 0, 0, 0);
            acc[a][jn] = MFMA16(ah[j], bl[jn], acc[a][jn], 0, 0, 0);
          }
        }
        __builtin_amdgcn_s_setprio(0);
      }
    }
    // per-pass min over a -> staggered LDS write (rows spread by quad q)
    float* dst = (wv < 4) ? umin_s : vmin_s;
    int cbase = (wv & 3) * 64 + gp * 32;
    #pragma unroll
    for (int jn = 0; jn < 2; ++jn) {
      int colg = cbase + jn * 16 + r15;
      int colx = colg ^ (q << 4);              // quad-staggered bank group
      #pragma unroll
      for (int rg = 0; rg < 4; ++rg) {
        float mm = acc[0][jn][rg];
        #pragma unroll
        for (int a = 1; a < 6; ++a) mm = fminf(mm, acc[a][jn][rg]);
        dst[(q * 4 + rg) * 256 + colx] = mm;
      }
    }
  }
  __syncthreads();   // all u/v mins in LDS

  // ---- combine: out = relu(umin + vmin + gfcn_b) (inverse stagger on read) --
  #pragma unroll
  for (int j = 0; j < 8; ++j) {
    int i = j * 512 + t;
    int r = i >> 8, g = i & 255;
    int gx = g ^ ((r >> 2) << 4);              // writer quad = r>>2
    out[(size_t)(b0 + r) * 256 + g] =
        fmaxf(umin_s[r * 256 + gx] + vmin_s[r * 256 + gx] + gfcn_b[g], 0.f);
  }
}

extern "C" void kernel_launch(void* const* d_in, const int* in_sizes, int n_in,
                              void* d_out, int out_size, void* d_ws, size_t ws_size,
                              hipStream_t stream) {
  const int* a_ids = (const int*)d_in[0];
  const int* b_ids = (const int*)d_in[1];
  const int* c_ids = (const int*)d_in[2];
  const int* event_ids = (const int*)d_in[3];
  const float* node_features = (const float*)d_in[4];
  const float* cond_rel = (const float*)d_in[5];
  const float* text = (const float*)d_in[6];
  const float* entity_emb = (const float*)d_in[7];
  const float* role_emb = (const float*)d_in[8];
  const float* node_W = (const float*)d_in[9];
  const float* node_b = (const float*)d_in[10];
  const float* conv_W = (const float*)d_in[11];
  const float* conv_b = (const float*)d_in[12];
  const float* bn_gamma = (const float*)d_in[13];
  const float* bn_beta = (const float*)d_in[14];
  const float* bn_mean = (const float*)d_in[15];
  const float* bn_var = (const float*)d_in[16];
  const float* gfcn_W = (const float*)d_in[17];
  const float* gfcn_b = (const float*)d_in[18];
  float* out = (float*)d_out;

  short* wsS = (short*)d_ws;
  float* bias_af = (float*)((char*)d_ws + OFF_BIAS_BYTES);
  const int B = in_sizes[0];   // 32768
  const int NT = B / 16;       // 2048

  setup_kernel<<<452, 256, 0, stream>>>(node_W, conv_W, gfcn_W, role_emb,
                                        conv_b, bn_gamma, bn_beta, bn_mean,
                                        bn_var, wsS, bias_af);
  fused2_kernel<<<NT, 512, 0, stream>>>(
      a_ids, b_ids, c_ids, event_ids, node_features, entity_emb, node_b,
      cond_rel, text, gfcn_b, wsS, bias_af, out);
}